// Round 13
// baseline (117.735 us; speedup 1.0000x reference)
//
#include <hip/hip_runtime.h>
#include <stdint.h>

#define VOCAB 32000
#define KDIM  2048   // 2*HIDDEN
#define NDIM  1024   // HIDDEN
#define MTOK  16384  // 4*4096

typedef __bf16 bf16x8 __attribute__((ext_vector_type(8)));
typedef float  f32x4  __attribute__((ext_vector_type(4)));

__device__ __forceinline__ uint32_t pkbf(float a, float b) {
    union { __bf16 h[2]; uint32_t u; } r;
    r.h[0] = (__bf16)a; r.h[1] = (__bf16)b;
    return r.u;
}

__device__ __forceinline__ unsigned short f2bf(float f) {  // fallback path only
    union { float f; uint32_t u; } v; v.f = f;
    uint32_t u = v.u;
    return (unsigned short)((u + 0x7FFFu + ((u >> 16) & 1u)) >> 16);
}

__device__ __forceinline__ void gload_lds16(const void* g, void* l) {
    __builtin_amdgcn_global_load_lds(
        (const __attribute__((address_space(1))) uint32_t*)g,
        (__attribute__((address_space(3))) uint32_t*)l,
        16, 0, 0);
}

// ---------------------------------------------------------------------------
// One-time transpose+convert: W1 [K][N] f32 -> W1T [N][K] bf16
// ---------------------------------------------------------------------------
__global__ void w1_transpose_kernel(const float* __restrict__ W1,
                                    unsigned short* __restrict__ W1T) {
    __shared__ unsigned short tile[32][33];
    const int k0 = blockIdx.x * 32;
    const int n0 = blockIdx.y * 32;
    const int tx = threadIdx.x;
    const int ty = threadIdx.y;
#pragma unroll
    for (int i = 0; i < 4; ++i) {
        int kl = ty + i * 8;
        tile[kl][tx] = __builtin_bit_cast(unsigned short,
                            (__bf16)W1[(size_t)(k0 + kl) * NDIM + n0 + tx]);
    }
    __syncthreads();
#pragma unroll
    for (int i = 0; i < 4; ++i) {
        int nl = ty + i * 8;
        W1T[(size_t)(n0 + nl) * KDIM + k0 + tx] = tile[tx][nl];
    }
}

// ---------------------------------------------------------------------------
// Pre-gather: Agat[m][k] bf16 = (idx[m]!=0 ? 32 : 0) * W0[idx[m]][k].
// Mask and sqrt(HIDDEN) scale folded here -> GEMM epilogue is a pure store.
// Memory-bound: reads ~128 MB fp32 (L3 absorbs dup rows), writes 64 MB bf16.
// ---------------------------------------------------------------------------
__global__ __launch_bounds__(256)
void pregather_kernel(const int* __restrict__ idx,
                      const float* __restrict__ W0,
                      unsigned short* __restrict__ Agat) {
    const int tid = threadIdx.x;
    const int sub = tid >> 5;            // 0..7: row within block
    const int l32 = tid & 31;
    const int m   = blockIdx.x * 8 + sub;
    const int token = idx[m];
    const float scl = (token != 0) ? 32.0f : 0.0f;
    const float* src = W0 + (size_t)token * KDIM;
    unsigned short* dst = Agat + (size_t)m * KDIM;
#pragma unroll
    for (int i = 0; i < 16; ++i) {
        const int k = (i * 32 + l32) * 4;
        f32x4 v = *(const f32x4*)(src + k);
        uint2 pk;
        pk.x = pkbf(v[0] * scl, v[1] * scl);
        pk.y = pkbf(v[2] * scl, v[3] * scl);
        *(uint2*)(dst + k) = pk;
    }
}

// ---------------------------------------------------------------------------
// m201-template 8-phase 256x256 GEMM, BOTH operands DMA-staged (A = Agat).
// BK=64, 2 K-tiles/iter, 512 thr = 8 waves (2M x 4N), wave out 128x64.
// Phase (mh,nh) quadrant: {8 A + 4 B ds_read_b128; 2 gload_lds; s_barrier;
//   setprio(1); 16 MFMA (full K=64); setprio(0); [vmcnt] ; s_barrier}.
// Staging ledger (T=2i; quarters q = 64 rows = 8KB = 1 gload/thread):
//   P0: A(T+1)q1,q3   P1: B(T+1)q0,q1   P2: B(T+1)q2,q3
//   P3: A(T+2)q0,q2 + vmcnt(2)          P4: A(T+2)q1,q3
//   P5: B(T+2)q0,q1   P6: B(T+2)q2,q3   P7: A(T+3)q0,q2 + vmcnt(2)
// FIFO-verified: P3's vmcnt(2) retires P0-P2 (tile T+1 complete before P4
// reads it); P7's retires P3-P6 (tile T+2 before next P0). Every staged
// region is >=1 full phase past its last read (bar2 + lgkm-before-MFMA
// ordering) -> race-free. Counted waits, never drain in steady state.
// ---------------------------------------------------------------------------
__global__ __launch_bounds__(512, 2)
void gemm8_kernel(const unsigned short* __restrict__ Agat,
                  const unsigned short* __restrict__ W1T,
                  float* __restrict__ out) {
    __shared__ __align__(16) char LdsA[2][32768];  // [buf][256 rows x 128B]
    __shared__ __align__(16) char LdsB[2][32768];

    const int tid  = threadIdx.x;
    const int lane = tid & 63;
    const int wav  = tid >> 6;
    const int wm   = wav >> 2;      // 0..1
    const int wn   = wav & 3;       // 0..3
    const int m0   = blockIdx.x * 256;
    const int n0   = blockIdx.y * 256;

    const int rl = lane & 15;
    const int kg = (lane >> 4) * 16;

    // staging sources: quarter q, wave covers rows q*64 + wav*8 .. +7
    const int gr = lane >> 3;            // row within 8-row group
    const int gc = (lane & 7) ^ gr;      // pre-swizzled 16B chunk
    const unsigned short* aSrc[4];
    const unsigned short* bSrc[4];
#pragma unroll
    for (int q = 0; q < 4; ++q) {
        aSrc[q] = Agat + (size_t)(m0 + q * 64 + wav * 8 + gr) * KDIM + gc * 8;
        bSrc[q] = W1T  + (size_t)(n0 + q * 64 + wav * 8 + gr) * KDIM + gc * 8;
    }

    f32x4 acc[2][2][4][2] = {};   // [mh][nh][mi][nbi] = 128 regs

#define STAGE_A(buf, q, t) \
    gload_lds16(aSrc[q] + (t) * 64, LdsA[buf] + (q) * 8192 + wav * 1024)
#define STAGE_B(buf, q, t) \
    gload_lds16(bSrc[q] + (t) * 64, LdsB[buf] + (q) * 8192 + wav * 1024)
#define VM2 asm volatile("s_waitcnt vmcnt(2)" ::: "memory")
#define VM0 asm volatile("s_waitcnt vmcnt(0)" ::: "memory")
#define NOPW (void)0

#define PHASE(buf, mh, nh, WAIT, ...)                                     \
    {                                                                     \
        bf16x8 A_[4][2], B_[2][2];                                        \
        _Pragma("unroll")                                                 \
        for (int mi = 0; mi < 4; ++mi) {                                  \
            const int r_ = wm * 128 + (mh) * 64 + mi * 16 + rl;           \
            _Pragma("unroll")                                             \
            for (int ks = 0; ks < 2; ++ks)                                \
                A_[mi][ks] = *(const bf16x8*)(LdsA[buf] +                 \
                    ((r_ * 128 + ks * 64 + kg) ^ ((r_ & 7) << 4)));       \
        }                                                                 \
        _Pragma("unroll")                                                 \
        for (int nbi = 0; nbi < 2; ++nbi) {                               \
            const int c_ = wn * 64 + (nh) * 32 + nbi * 16 + rl;           \
            _Pragma("unroll")                                             \
            for (int ks = 0; ks < 2; ++ks)                                \
                B_[nbi][ks] = *(const bf16x8*)(LdsB[buf] +                \
                    ((c_ * 128 + ks * 64 + kg) ^ ((c_ & 7) << 4)));       \
        }                                                                 \
        __VA_ARGS__;                                                      \
        __builtin_amdgcn_s_barrier();                                     \
        __builtin_amdgcn_s_setprio(1);                                    \
        _Pragma("unroll")                                                 \
        for (int ks = 0; ks < 2; ++ks)                                    \
            _Pragma("unroll")                                             \
            for (int mi = 0; mi < 4; ++mi)                                \
                _Pragma("unroll")                                         \
                for (int nbi = 0; nbi < 2; ++nbi)                         \
                    acc[mh][nh][mi][nbi] =                                \
                        __builtin_amdgcn_mfma_f32_16x16x32_bf16(          \
                            A_[mi][ks], B_[nbi][ks],                      \
                            acc[mh][nh][mi][nbi], 0, 0, 0);               \
        __builtin_amdgcn_s_setprio(0);                                    \
        WAIT;                                                             \
        __builtin_amdgcn_s_barrier();                                     \
    }

    // ---- prologue: tile 0 complete (8 ops) + A(1) q0,q2 in flight ----
    STAGE_A(0, 0, 0); STAGE_A(0, 1, 0); STAGE_A(0, 2, 0); STAGE_A(0, 3, 0);
    STAGE_B(0, 0, 0); STAGE_B(0, 1, 0); STAGE_B(0, 2, 0); STAGE_B(0, 3, 0);
    STAGE_A(1, 0, 1); STAGE_A(1, 2, 1);
    VM2;
    __builtin_amdgcn_s_barrier();

    // ---- main loop: 16 iterations x 2 K-tiles ----
    for (int i = 0; i < 16; ++i) {
        const int T = 2 * i;
        const bool s2 = (T + 2 < 32);   // stage tile T+2?
        const bool s3 = (T + 3 < 32);   // stage A(T+3) lead quarters?

        // tile T (buf0)
        PHASE(0, 0, 0, NOPW, STAGE_A(1, 1, T + 1); STAGE_A(1, 3, T + 1))
        PHASE(0, 0, 1, NOPW, STAGE_B(1, 0, T + 1); STAGE_B(1, 1, T + 1))
        PHASE(0, 1, 0, NOPW, STAGE_B(1, 2, T + 1); STAGE_B(1, 3, T + 1))
        PHASE(0, 1, 1, { if (s2) { VM2; } else { VM0; } },
              if (s2) { STAGE_A(0, 0, T + 2); STAGE_A(0, 2, T + 2); })
        // tile T+1 (buf1)
        PHASE(1, 0, 0, NOPW,
              if (s2) { STAGE_A(0, 1, T + 2); STAGE_A(0, 3, T + 2); })
        PHASE(1, 0, 1, NOPW,
              if (s2) { STAGE_B(0, 0, T + 2); STAGE_B(0, 1, T + 2); })
        PHASE(1, 1, 0, NOPW,
              if (s2) { STAGE_B(0, 2, T + 2); STAGE_B(0, 3, T + 2); })
        PHASE(1, 1, 1, { if (s2) { VM2; } },
              if (s3) { STAGE_A(1, 0, T + 3); STAGE_A(1, 2, T + 3); })
    }

    // ---- epilogue: pure store (mask+scale folded into Agat) ----
    const int rq = (lane >> 4) * 4;
#pragma unroll
    for (int mh = 0; mh < 2; ++mh)
#pragma unroll
    for (int nh = 0; nh < 2; ++nh)
#pragma unroll
    for (int mi = 0; mi < 4; ++mi)
#pragma unroll
    for (int rr = 0; rr < 4; ++rr) {
        const int m = m0 + wm * 128 + mh * 64 + mi * 16 + rq + rr;
#pragma unroll
        for (int nbi = 0; nbi < 2; ++nbi) {
            const int n = n0 + wn * 64 + nh * 32 + nbi * 16 + rl;
            out[(size_t)m * NDIM + n] = acc[mh][nh][mi][nbi][rr];
        }
    }
#undef STAGE_A
#undef STAGE_B
#undef VM2
#undef VM0
#undef NOPW
#undef PHASE
}

// ---------------------------------------------------------------------------
// Fallback (ws too small): single-buffer, transpose-on-stage from W1 fp32.
// ---------------------------------------------------------------------------
__global__ __launch_bounds__(256)
void emb_gemm_nows(const int* __restrict__ idx,
                   const float* __restrict__ W0,
                   const float* __restrict__ W1,
                   float* __restrict__ out) {
    __shared__ __align__(16) char A_lds[128 * 128];
    __shared__ __align__(16) char B_lds[128 * 128];

    const int tid  = threadIdx.x;
    const int lane = tid & 63;
    const int wav  = tid >> 6;
    const int wm = wav >> 1;
    const int wn = wav & 1;
    const int m0 = blockIdx.x * 128;
    const int n0 = blockIdx.y * 128;

    const float* aSrc[8];
    int arow[8];
#pragma unroll
    for (int it = 0; it < 8; ++it) {
        int r = it * 16 + (tid >> 4);
        arow[it] = r;
        aSrc[it] = W0 + (size_t)idx[m0 + r] * KDIM;
    }
    const int acol4 = tid & 15;

    f32x4 acc[4][4] = {};

    for (int k0 = 0; k0 < KDIM; k0 += 64) {
#pragma unroll
        for (int it = 0; it < 8; ++it) {
            const int r = arow[it];
            const float4 v = *(const float4*)(aSrc[it] + k0 + acol4 * 4);
            uint2 pk;
            pk.x = pkbf(v.x, v.y);
            pk.y = pkbf(v.z, v.w);
            *(uint2*)(A_lds + ((r * 128 + acol4 * 8) ^ ((r & 7) << 4))) = pk;
        }
#pragma unroll
        for (int it = 0; it < 8; ++it) {
            const int k  = it * 8 + (tid >> 5);
            const int n4 = (tid & 31) * 4;
            const float4 v = *(const float4*)(W1 + (size_t)(k0 + k) * NDIM + n0 + n4);
            unsigned short h[4] = { f2bf(v.x), f2bf(v.y), f2bf(v.z), f2bf(v.w) };
#pragma unroll
            for (int i = 0; i < 4; ++i) {
                const int n = n4 + i;
                *(unsigned short*)(B_lds + ((n * 128 + k * 2) ^ ((n & 7) << 4))) = h[i];
            }
        }
        __syncthreads();

#pragma unroll
        for (int ks = 0; ks < 2; ++ks) {
            const int kb = ks * 64 + (lane >> 4) * 16;
            bf16x8 af[4], bfv[4];
#pragma unroll
            for (int mi = 0; mi < 4; ++mi) {
                const int r = wm * 64 + mi * 16 + (lane & 15);
                af[mi] = *(const bf16x8*)(A_lds + ((r * 128 + kb) ^ ((r & 7) << 4)));
            }
#pragma unroll
            for (int ni = 0; ni < 4; ++ni) {
                const int n = wn * 64 + ni * 16 + (lane & 15);
                bfv[ni] = *(const bf16x8*)(B_lds + ((n * 128 + kb) ^ ((n & 7) << 4)));
            }
#pragma unroll
            for (int mi = 0; mi < 4; ++mi)
#pragma unroll
                for (int ni = 0; ni < 4; ++ni)
                    acc[mi][ni] = __builtin_amdgcn_mfma_f32_16x16x32_bf16(
                        af[mi], bfv[ni], acc[mi][ni], 0, 0, 0);
        }
        __syncthreads();
    }

    const int col  = lane & 15;
    const int rowq = (lane >> 4) * 4;
#pragma unroll
    for (int mi = 0; mi < 4; ++mi) {
#pragma unroll
        for (int r = 0; r < 4; ++r) {
            const int m = m0 + wm * 64 + mi * 16 + rowq + r;
            const float msk = (idx[m] != 0) ? 32.0f : 0.0f;
#pragma unroll
            for (int ni = 0; ni < 4; ++ni) {
                const int n = n0 + wn * 64 + ni * 16 + col;
                out[(size_t)m * NDIM + n] = acc[mi][ni][r] * msk;
            }
        }
    }
}

extern "C" void kernel_launch(void* const* d_in, const int* in_sizes, int n_in,
                              void* d_out, int out_size, void* d_ws, size_t ws_size,
                              hipStream_t stream) {
    const int*   idx = (const int*)d_in[0];
    const float* W0  = (const float*)d_in[1];
    const float* W1  = (const float*)d_in[2];
    float*       out = (float*)d_out;

    const size_t w1t_bytes  = (size_t)KDIM * NDIM * 2;   // 4 MB
    const size_t agat_bytes = (size_t)MTOK * KDIM * 2;   // 64 MB

    if (ws_size >= w1t_bytes + agat_bytes) {
        unsigned short* W1T  = (unsigned short*)d_ws;
        unsigned short* Agat = (unsigned short*)((char*)d_ws + w1t_bytes);

        dim3 tgrid(KDIM / 32, NDIM / 32);
        w1_transpose_kernel<<<tgrid, dim3(32, 8), 0, stream>>>(W1, W1T);
        pregather_kernel<<<MTOK / 8, 256, 0, stream>>>(idx, W0, Agat);
        dim3 grid(MTOK / 256, NDIM / 256);  // (64, 4) = 256 blocks = 1/CU
        gemm8_kernel<<<grid, 512, 0, stream>>>(Agat, W1T, out);
    } else {
        dim3 grid(MTOK / 128, NDIM / 128);
        emb_gemm_nows<<<grid, 256, 0, stream>>>(idx, W0, W1, out);
    }
}

// Round 14
// 89.209 us; speedup vs baseline: 1.3198x; 1.3198x over previous
//
#include <hip/hip_runtime.h>
#include <stdint.h>

#define VOCAB 32000
#define KDIM  2048   // 2*HIDDEN
#define NDIM  1024   // HIDDEN
#define MTOK  16384  // 4*4096

typedef __bf16 bf16x8 __attribute__((ext_vector_type(8)));
typedef float  f32x4  __attribute__((ext_vector_type(4)));

__device__ __forceinline__ uint32_t pkbf(float a, float b) {
    union { __bf16 h[2]; uint32_t u; } r;
    r.h[0] = (__bf16)a; r.h[1] = (__bf16)b;
    return r.u;
}

__device__ __forceinline__ unsigned short f2bf(float f) {  // fallback path only
    union { float f; uint32_t u; } v; v.f = f;
    uint32_t u = v.u;
    return (unsigned short)((u + 0x7FFFu + ((u >> 16) & 1u)) >> 16);
}

// width-16 global->LDS DMA: per-lane global src, wave-uniform LDS base.
__device__ __forceinline__ void gload_lds16(const void* g, void* l) {
    __builtin_amdgcn_global_load_lds(
        (const __attribute__((address_space(1))) uint32_t*)g,
        (__attribute__((address_space(3))) uint32_t*)l,
        16, 0, 0);
}

// ---------------------------------------------------------------------------
// One-time transpose+convert: W1 [K][N] f32 -> W1T [N][K] bf16
// ---------------------------------------------------------------------------
__global__ void w1_transpose_kernel(const float* __restrict__ W1,
                                    unsigned short* __restrict__ W1T) {
    __shared__ unsigned short tile[32][33];
    const int k0 = blockIdx.x * 32;
    const int n0 = blockIdx.y * 32;
    const int tx = threadIdx.x;
    const int ty = threadIdx.y;
#pragma unroll
    for (int i = 0; i < 4; ++i) {
        int kl = ty + i * 8;
        tile[kl][tx] = __builtin_bit_cast(unsigned short,
                            (__bf16)W1[(size_t)(k0 + kl) * NDIM + n0 + tx]);
    }
    __syncthreads();
#pragma unroll
    for (int i = 0; i < 4; ++i) {
        int nl = ty + i * 8;
        W1T[(size_t)(n0 + nl) * KDIM + k0 + tx] = tile[tx][nl];
    }
}

// ---------------------------------------------------------------------------
// FINAL (best measured: 88.8 us, R12): 256x256 fused gather-GEMM, R7
// relaxed-barrier structure + wave-parity K-half skew. Odd waves consume ks
// order (1,0), even waves (0,1) — legal post-barrier (whole tile resident),
// deterministic (per-thread accumulation order fixed). BK=64, 512 thr =
// 8 waves (2M x 4N), wave tile 128x64, acc 128 AGPR, dbuf LDS 128 KB,
// ONE __syncthreads per K-tile (all intra-tile reads hit buf[cur], all
// staging writes hit buf[nxt]). A: gathered W0 rows, fp32->bf16 in regs,
// half-gathers issued early (T14). B: global_load_lds w16 from W1T with
// pre-swizzled source chunks (rule 21). XOR swizzle byte^=(r&7)<<4 on both
// tiles (2-way alias = free). VGPR ~= 110 + 128 acc <= 256/wave at
// 2 waves/SIMD -> no spill (WRITE_SIZE == 65.5 MB exactly).
// Structural ceiling validated by R8-R13 escape attempts (all >= this).
// ---------------------------------------------------------------------------
__global__ __launch_bounds__(512, 2)
void emb_gemm_ws(const int* __restrict__ idx,
                 const float* __restrict__ W0,
                 const unsigned short* __restrict__ W1T,
                 float* __restrict__ out) {
    __shared__ __align__(16) char Abuf[2][256 * 128];  // 256 rows x 64 bf16
    __shared__ __align__(16) char Bbuf[2][256 * 128];

    const int tid  = threadIdx.x;   // 0..511
    const int lane = tid & 63;
    const int wav  = tid >> 6;      // 0..7
    const int wm   = wav >> 2;      // 0..1  (M half: 128 rows)
    const int wn   = wav & 3;       // 0..3  (N quarter: 64 cols)
    const int m0   = blockIdx.x * 256;
    const int n0   = blockIdx.y * 256;

    const int rl = lane & 15;
    const int kg = (lane >> 4) * 16;  // 16B k-subchunk within 64B half

    // wave-parity K-half skew
    const int ka = wav & 1;
    const int kb = ka ^ 1;

    // ---- A gather setup: 8 chunks/thread (16B fp32 -> 8B bf16) ----
    const int ac = tid & 15;
    uint32_t aoff[8];
    int abyte[8];
#pragma unroll
    for (int it = 0; it < 8; ++it) {
        const int r = (tid >> 4) + it * 32;          // 0..255
        aoff[it]  = ((uint32_t)idx[m0 + r] * KDIM + ac * 4) * 4u;
        abyte[it] = (r * 128 + ac * 8) ^ ((r & 7) << 4);
    }

    // ---- B staging: 4 gload_lds/wave (8 rows each), pre-swizzled source ----
    const int brin = lane >> 3;
    const int bch  = (lane & 7) ^ brin;
    uint32_t boff[4];
    int bbase[4];
#pragma unroll
    for (int i = 0; i < 4; ++i) {
        const int rg = wav * 32 + i * 8;  // wave-uniform 8-row group base
        boff[i]  = ((uint32_t)(n0 + rg + brin) * KDIM + bch * 8) * 2u;
        bbase[i] = rg * 128;
    }

    f32x4 apre[4];        // one half-gather live at a time (16 VGPR)
    f32x4 acc[8][4] = {};
    bf16x8 af[4], bf2[4], bfv[4];

#define ISSUE_A_H(t, h)                                              \
    _Pragma("unroll")                                                \
    for (int j = 0; j < 4; ++j)                                      \
        apre[j] = *(const f32x4*)((const char*)W0 + aoff[(h) * 4 + j] + (t) * 256);

#define WRITE_A_H(buf, h)                                            \
    _Pragma("unroll")                                                \
    for (int j = 0; j < 4; ++j) {                                    \
        uint2 pk_;                                                   \
        pk_.x = pkbf(apre[j][0], apre[j][1]);                        \
        pk_.y = pkbf(apre[j][2], apre[j][3]);                        \
        *(uint2*)(Abuf[buf] + abyte[(h) * 4 + j]) = pk_;             \
    }

#define DMA_B(buf, t)                                                \
    _Pragma("unroll")                                                \
    for (int i = 0; i < 4; ++i)                                      \
        gload_lds16((const char*)W1T + boff[i] + (t) * 128,          \
                    Bbuf[buf] + bbase[i]);

#define READ_A(buf, ks, mh, dst)                                     \
    _Pragma("unroll")                                                \
    for (int mi = 0; mi < 4; ++mi) {                                 \
        const int r = wm * 128 + (mh) * 64 + mi * 16 + rl;           \
        dst[mi] = *(const bf16x8*)(Abuf[buf] +                       \
            ((r * 128 + (ks) * 64 + kg) ^ ((r & 7) << 4)));          \
    }

#define READ_B(buf, ks, dst)                                         \
    _Pragma("unroll")                                                \
    for (int ni = 0; ni < 4; ++ni) {                                 \
        const int n = wn * 64 + ni * 16 + rl;                        \
        dst[ni] = *(const bf16x8*)(Bbuf[buf] +                       \
            ((n * 128 + (ks) * 64 + kg) ^ ((n & 7) << 4)));          \
    }

#define MFMA16(a_, b_, mh)                                           \
    __builtin_amdgcn_s_setprio(1);                                   \
    _Pragma("unroll")                                                \
    for (int mi = 0; mi < 4; ++mi)                                   \
        _Pragma("unroll")                                            \
        for (int ni = 0; ni < 4; ++ni)                               \
            acc[(mh) * 4 + mi][ni] =                                 \
                __builtin_amdgcn_mfma_f32_16x16x32_bf16(             \
                    a_[mi], b_[ni], acc[(mh) * 4 + mi][ni], 0, 0, 0);\
    __builtin_amdgcn_s_setprio(0);

    // ---- prologue: stage K-tile 0 into buf0 ----
    DMA_B(0, 0);
    ISSUE_A_H(0, 0); WRITE_A_H(0, 0);
    ISSUE_A_H(0, 1); WRITE_A_H(0, 1);   // vmcnt wait also retires B DMA
    __syncthreads();

    // ---- main loop: 32 K-tiles, one barrier per tile, skewed ks order ----
    for (int t = 0; t < 32; ++t) {
        const int cur = t & 1, nxt = cur ^ 1;
        const bool pf = (t < 31);

        // issue next tile's B DMA + first A half-gather up front
        if (pf) { DMA_B(nxt, t + 1); ISSUE_A_H(t + 1, 0); }

        // first K-half (ka: 0 for even waves, 1 for odd)
        READ_B(cur, ka, bfv);
        READ_A(cur, ka, 0, af);
        MFMA16(af, bfv, 0);
        READ_A(cur, ka, 1, af);
        MFMA16(af, bfv, 1);

        // mid-tile staging: write A(t+1) half 0 (loads ~2 clusters old)
        if (pf) { WRITE_A_H(nxt, 0); ISSUE_A_H(t + 1, 1); }

        // second K-half (kb)
        READ_B(cur, kb, bf2);
        READ_A(cur, kb, 0, af);
        MFMA16(af, bf2, 0);
        READ_A(cur, kb, 1, af);
        MFMA16(af, bf2, 1);

        if (pf) { WRITE_A_H(nxt, 1); }
        __syncthreads();   // drains A ds_writes + B DMA; buffer flip
    }

    // ---- epilogue: mask (token==0) and scale by 32 = sqrt(1024) ----
    const int rowq = (lane >> 4) * 4;
#pragma unroll
    for (int mi = 0; mi < 8; ++mi) {
#pragma unroll
        for (int r = 0; r < 4; ++r) {
            const int m = m0 + wm * 128 + mi * 16 + rowq + r;
            const float msk = (idx[m] != 0) ? 32.0f : 0.0f;
#pragma unroll
            for (int ni = 0; ni < 4; ++ni) {
                const int n = n0 + wn * 64 + ni * 16 + rl;
                out[(size_t)m * NDIM + n] = acc[mi][ni][r] * msk;
            }
        }
    }
#undef ISSUE_A_H
#undef WRITE_A_H
#undef DMA_B
#undef READ_A
#undef READ_B
#undef MFMA16
}

// ---------------------------------------------------------------------------
// Fallback (ws too small): single-buffer, transpose-on-stage from W1 fp32.
// ---------------------------------------------------------------------------
__global__ __launch_bounds__(256)
void emb_gemm_nows(const int* __restrict__ idx,
                   const float* __restrict__ W0,
                   const float* __restrict__ W1,
                   float* __restrict__ out) {
    __shared__ __align__(16) char A_lds[128 * 128];
    __shared__ __align__(16) char B_lds[128 * 128];

    const int tid  = threadIdx.x;
    const int lane = tid & 63;
    const int wav  = tid >> 6;
    const int wm = wav >> 1;
    const int wn = wav & 1;
    const int m0 = blockIdx.x * 128;
    const int n0 = blockIdx.y * 128;

    const float* aSrc[8];
    int arow[8];
#pragma unroll
    for (int it = 0; it < 8; ++it) {
        int r = it * 16 + (tid >> 4);
        arow[it] = r;
        aSrc[it] = W0 + (size_t)idx[m0 + r] * KDIM;
    }
    const int acol4 = tid & 15;

    f32x4 acc[4][4] = {};

    for (int k0 = 0; k0 < KDIM; k0 += 64) {
#pragma unroll
        for (int it = 0; it < 8; ++it) {
            const int r = arow[it];
            const float4 v = *(const float4*)(aSrc[it] + k0 + acol4 * 4);
            uint2 pk;
            pk.x = pkbf(v.x, v.y);
            pk.y = pkbf(v.z, v.w);
            *(uint2*)(A_lds + ((r * 128 + acol4 * 8) ^ ((r & 7) << 4))) = pk;
        }
#pragma unroll
        for (int it = 0; it < 8; ++it) {
            const int k  = it * 8 + (tid >> 5);
            const int n4 = (tid & 31) * 4;
            const float4 v = *(const float4*)(W1 + (size_t)(k0 + k) * NDIM + n0 + n4);
            unsigned short h[4] = { f2bf(v.x), f2bf(v.y), f2bf(v.z), f2bf(v.w) };
#pragma unroll
            for (int i = 0; i < 4; ++i) {
                const int n = n4 + i;
                *(unsigned short*)(B_lds + ((n * 128 + k * 2) ^ ((n & 7) << 4))) = h[i];
            }
        }
        __syncthreads();

#pragma unroll
        for (int ks = 0; ks < 2; ++ks) {
            const int kb = ks * 64 + (lane >> 4) * 16;
            bf16x8 af[4], bfv[4];
#pragma unroll
            for (int mi = 0; mi < 4; ++mi) {
                const int r = wm * 64 + mi * 16 + (lane & 15);
                af[mi] = *(const bf16x8*)(A_lds + ((r * 128 + kb) ^ ((r & 7) << 4)));
            }
#pragma unroll
            for (int ni = 0; ni < 4; ++ni) {
                const int n = wn * 64 + ni * 16 + (lane & 15);
                bfv[ni] = *(const bf16x8*)(B_lds + ((n * 128 + kb) ^ ((n & 7) << 4)));
            }
#pragma unroll
            for (int mi = 0; mi < 4; ++mi)
#pragma unroll
                for (int ni = 0; ni < 4; ++ni)
                    acc[mi][ni] = __builtin_amdgcn_mfma_f32_16x16x32_bf16(
                        af[mi], bfv[ni], acc[mi][ni], 0, 0, 0);
        }
        __syncthreads();
    }

    const int col  = lane & 15;
    const int rowq = (lane >> 4) * 4;
#pragma unroll
    for (int mi = 0; mi < 4; ++mi) {
#pragma unroll
        for (int r = 0; r < 4; ++r) {
            const int m = m0 + wm * 64 + mi * 16 + rowq + r;
            const float msk = (idx[m] != 0) ? 32.0f : 0.0f;
#pragma unroll
            for (int ni = 0; ni < 4; ++ni) {
                const int n = n0 + wn * 64 + ni * 16 + col;
                out[(size_t)m * NDIM + n] = acc[mi][ni][r] * msk;
            }
        }
    }
}

extern "C" void kernel_launch(void* const* d_in, const int* in_sizes, int n_in,
                              void* d_out, int out_size, void* d_ws, size_t ws_size,
                              hipStream_t stream) {
    const int*   idx = (const int*)d_in[0];
    const float* W0  = (const float*)d_in[1];
    const float* W1  = (const float*)d_in[2];
    float*       out = (float*)d_out;

    const size_t w1t_bytes = (size_t)KDIM * NDIM * 2;

    if (ws_size >= w1t_bytes) {
        unsigned short* W1T = (unsigned short*)d_ws;
        dim3 tgrid(KDIM / 32, NDIM / 32);
        w1_transpose_kernel<<<tgrid, dim3(32, 8), 0, stream>>>(W1, W1T);
        dim3 grid(MTOK / 256, NDIM / 256);  // (64, 4) = 256 blocks = 1/CU
        emb_gemm_ws<<<grid, 512, 0, stream>>>(idx, W0, W1T, out);
    } else {
        dim3 grid(MTOK / 128, NDIM / 128);
        emb_gemm_nows<<<grid, 256, 0, stream>>>(idx, W0, W1, out);
    }
}